// Round 1
// baseline (432.060 us; speedup 1.0000x reference)
//
#include <hip/hip_runtime.h>
#include <hip/hip_cooperative_groups.h>

namespace cg = cooperative_groups;

// Problem constants: B=64, C=512, H=W=32, N=1, A=16
#define B_DIM 64
#define C_DIM 512
#define A_DIM 16
#define HW    1024
#define EPS   1e-5f

#define NBLK       1024
#define WAVES_PB   4
#define NWAVE      (NBLK * WAVES_PB)                 // 4096 waves
#define ROWS_PER_WAVE ((B_DIM * C_DIM) / NWAVE)      // 8

// ---------------------------------------------------------------------------
// Single cooperative kernel, 3 phases separated by grid.sync():
//  P1: per-(b,c) row sums of x (each wave: 8 contiguous rows, 4 float4/lane,
//      wave-shfl reduction only — no LDS, no __syncthreads).
//  P2: waves [0,512): per-channel batch stats + pooled new_x.
//      waves [512,528): LayerNorm of router_weights^T rows -> wn_t[c][a].
//  P3: waves [0,64): logits = new_x . wn + bias; softmax over A.
// ---------------------------------------------------------------------------
__global__ __launch_bounds__(256, 4) void fused_router(
    const float* __restrict__ x,
    const float* __restrict__ rw,
    const float* __restrict__ rbias,
    const float* __restrict__ bn_g,
    const float* __restrict__ bn_b,
    const float* __restrict__ ln_g,
    const float* __restrict__ ln_b,
    float* __restrict__ newx,
    float* __restrict__ logits,
    float* __restrict__ probs,
    float* __restrict__ s1,
    float* __restrict__ sq,
    float* __restrict__ wn_t)
{
    const int lane = threadIdx.x & 63;
    const int gw   = blockIdx.x * WAVES_PB + (threadIdx.x >> 6);  // 0..4095

    // ---- Phase 1: row sums (reads all of x exactly once, coalesced) ----
#pragma unroll
    for (int i = 0; i < ROWS_PER_WAVE; ++i) {
        const int row = gw * ROWS_PER_WAVE + i;      // row = b*C + c
        const float4* p = reinterpret_cast<const float4*>(x + (size_t)row * HW);
        float s = 0.f, q = 0.f;
#pragma unroll
        for (int j = 0; j < 4; ++j) {
            const float4 v = p[lane + 64 * j];
            s += v.x + v.y + v.z + v.w;
            q += v.x * v.x + v.y * v.y + v.z * v.z + v.w * v.w;
        }
#pragma unroll
        for (int off = 32; off > 0; off >>= 1) {
            s += __shfl_down(s, off);
            q += __shfl_down(q, off);
        }
        if (lane == 0) {
            const int b = row >> 9;                  // row / C_DIM
            const int c = row & (C_DIM - 1);
            s1[c * B_DIM + b] = s;                   // [c][b] -> coalesced in P2
            sq[c * B_DIM + b] = q;
        }
    }

    cg::this_grid().sync();

    // ---- Phase 2 ----
    if (gw < C_DIM) {
        // per-channel batch stats + pooled new_x (lane == b)
        const int c = gw;
        const float s = s1[c * B_DIM + lane];
        const float q = sq[c * B_DIM + lane];
        float ts = s, tq = q;
#pragma unroll
        for (int off = 32; off > 0; off >>= 1) {
            ts += __shfl_down(ts, off);
            tq += __shfl_down(tq, off);
        }
        const float mu  = __shfl(ts, 0) * (1.0f / 65536.0f);   // /(B*H*W)
        const float var = __shfl(tq, 0) * (1.0f / 65536.0f) - mu * mu;
        const float r   = rsqrtf(var + EPS);
        newx[lane * C_DIM + c] = bn_g[c] * (s * (1.0f / 1024.0f) - mu) * r + bn_b[c];
    } else if (gw < C_DIM + A_DIM) {
        // LayerNorm over C of router_weights[:,a]
        const int a = gw - C_DIM;
        float wv[8];
        float s = 0.f, q = 0.f;
#pragma unroll
        for (int j = 0; j < 8; ++j) {
            wv[j] = rw[(j * 64 + lane) * A_DIM + a];
            s += wv[j];
            q += wv[j] * wv[j];
        }
#pragma unroll
        for (int off = 32; off > 0; off >>= 1) {
            s += __shfl_down(s, off);
            q += __shfl_down(q, off);
        }
        const float m = __shfl(s, 0) * (1.0f / 512.0f);
        const float v = __shfl(q, 0) * (1.0f / 512.0f) - m * m;
        const float r = rsqrtf(v + EPS);
#pragma unroll
        for (int j = 0; j < 8; ++j) {
            const int c = j * 64 + lane;
            wn_t[c * A_DIM + a] = (wv[j] - m) * r * ln_g[c] + ln_b[c];
        }
    }

    cg::this_grid().sync();

    // ---- Phase 3: matvec + softmax (wave gw handles batch row b = gw) ----
    if (gw < B_DIM) {
        const int b = gw;
        const int a = lane & 15;
        const int chunk = lane >> 4;
        const float* xr = newx + b * C_DIM + chunk * 128;
        const float* wr = wn_t + (chunk * 128) * A_DIM + a;
        float acc = 0.f;
#pragma unroll 8
        for (int i = 0; i < 128; i++) {
            acc += xr[i] * wr[i * A_DIM];
        }
        acc += __shfl_xor(acc, 16);
        acc += __shfl_xor(acc, 32);
        const float logit = acc + rbias[a];
        float mx = logit;
#pragma unroll
        for (int m = 1; m < 16; m <<= 1) mx = fmaxf(mx, __shfl_xor(mx, m));
        const float e = expf(logit - mx);
        float se = e;
#pragma unroll
        for (int m = 1; m < 16; m <<= 1) se += __shfl_xor(se, m);
        if (lane < 16) {                             // lane == a
            logits[b * A_DIM + lane] = logit;
            probs[b * A_DIM + lane] = e / se;
        }
    }
}

extern "C" void kernel_launch(void* const* d_in, const int* in_sizes, int n_in,
                              void* d_out, int out_size, void* d_ws, size_t ws_size,
                              hipStream_t stream) {
    const float* x     = (const float*)d_in[0];   // [B,C,H,W]
    const float* rw    = (const float*)d_in[1];   // [1,C,A]
    const float* rbias = (const float*)d_in[2];   // [1,A]
    const float* bn_g  = (const float*)d_in[3];   // [1,C]
    const float* bn_b  = (const float*)d_in[4];
    const float* ln_g  = (const float*)d_in[5];
    const float* ln_b  = (const float*)d_in[6];

    float* out    = (float*)d_out;
    float* newx   = out;                          // 32768 floats: new_x [1,64,512]
    float* logits = out + B_DIM * C_DIM;          // 1024 floats
    float* probs  = logits + B_DIM * A_DIM;       // 1024 floats

    float* s1   = (float*)d_ws;                   // 32768 floats  [c][b]
    float* sq   = s1 + B_DIM * C_DIM;             // 32768 floats  [c][b]
    float* wn_t = sq + B_DIM * C_DIM;             // 8192 floats   [c][a]

    void* args[] = { (void*)&x, (void*)&rw, (void*)&rbias, (void*)&bn_g,
                     (void*)&bn_b, (void*)&ln_g, (void*)&ln_b,
                     (void*)&newx, (void*)&logits, (void*)&probs,
                     (void*)&s1, (void*)&sq, (void*)&wn_t };

    hipLaunchCooperativeKernel((const void*)fused_router, dim3(NBLK), dim3(256),
                               args, 0, stream);
}

// Round 2
// 209.709 us; speedup vs baseline: 2.0603x; 2.0603x over previous
//
#include <hip/hip_runtime.h>

// Problem constants (from reference): B=64, C=512, H=W=32, N=1, A=16
#define B_DIM 64
#define C_DIM 512
#define A_DIM 16
#define HW    1024           // H*W
#define EPS   1e-5f

// ---------------------------------------------------------------------------
// Kernel 1: per-(b,c) row reduction of x (contiguous 1024 floats each).
// One WAVE per row (no LDS, no __syncthreads): 4 float4/lane, 6-level shfl.
// 1024-thread blocks = 16 waves = 16 rows/block; grid = 2048 blocks.
// Writes sqs[c*B + b] = {sum, sumsq} as float2 (one 8B store per row).
// ---------------------------------------------------------------------------
__global__ __launch_bounds__(1024) void reduce_rows(const float* __restrict__ x,
                                                    float2* __restrict__ sqs) {
    const int wid  = threadIdx.x >> 6;               // 0..15
    const int lane = threadIdx.x & 63;
    const int row  = blockIdx.x * 16 + wid;          // = b*C + c (x row-major)
    const float4* p = reinterpret_cast<const float4*>(x + (size_t)row * HW);
    float s = 0.f, q = 0.f;
#pragma unroll
    for (int j = 0; j < 4; ++j) {                    // 1 KB/instr, coalesced
        const float4 v = p[lane + 64 * j];
        s += v.x + v.y + v.z + v.w;
        q += v.x * v.x + v.y * v.y + v.z * v.z + v.w * v.w;
    }
#pragma unroll
    for (int off = 32; off > 0; off >>= 1) {
        s += __shfl_down(s, off);
        q += __shfl_down(q, off);
    }
    if (lane == 0) {
        const int b = row >> 9;                      // row / C_DIM
        const int c = row & (C_DIM - 1);
        sqs[c * B_DIM + b] = make_float2(s, q);      // [c][b] -> coalesced in K2
    }
}

// ---------------------------------------------------------------------------
// Kernel 2: blocks [0,512): per-channel batch stats + new_x.
//           blocks [512,528): LayerNorm of router_weights^T rows -> wn_t[c][a].
// 64 threads = 1 wave per block.
// ---------------------------------------------------------------------------
__global__ __launch_bounds__(64) void stats_newx_ln(
    const float2* __restrict__ sqs,
    const float* __restrict__ bn_g, const float* __restrict__ bn_b,
    const float* __restrict__ rw, const float* __restrict__ ln_g,
    const float* __restrict__ ln_b,
    float* __restrict__ newx, float* __restrict__ wn_t) {
    const int lane = threadIdx.x;
    if (blockIdx.x < C_DIM) {
        // --- batch-norm stats for channel c + pooled new_x ---
        const int c = blockIdx.x;
        const float2 v = sqs[c * B_DIM + lane];      // lane == b, 8B coalesced
        float ts = v.x, tq = v.y;
#pragma unroll
        for (int off = 32; off > 0; off >>= 1) {
            ts += __shfl_down(ts, off);
            tq += __shfl_down(tq, off);
        }
        const float mu  = __shfl(ts, 0) * (1.0f / 65536.0f);   // /(B*H*W)
        const float var = __shfl(tq, 0) * (1.0f / 65536.0f) - mu * mu;
        const float r   = rsqrtf(var + EPS);
        const float nx  = bn_g[c] * (v.x * (1.0f / 1024.0f) - mu) * r + bn_b[c];
        newx[lane * C_DIM + c] = nx;                 // new_x[b][c]
    } else {
        // --- LayerNorm over C of router_weights[:,a] (i.e. W^T row a) ---
        const int a = blockIdx.x - C_DIM;
        float wv[8];
        float s = 0.f, q = 0.f;
#pragma unroll
        for (int j = 0; j < 8; j++) {
            const int c = j * 64 + lane;
            wv[j] = rw[c * A_DIM + a];
            s += wv[j];
            q += wv[j] * wv[j];
        }
#pragma unroll
        for (int off = 32; off > 0; off >>= 1) {
            s += __shfl_down(s, off);
            q += __shfl_down(q, off);
        }
        const float m = __shfl(s, 0) * (1.0f / 512.0f);
        const float v = __shfl(q, 0) * (1.0f / 512.0f) - m * m;
        const float r = rsqrtf(v + EPS);
#pragma unroll
        for (int j = 0; j < 8; j++) {
            const int c = j * 64 + lane;
            wn_t[c * A_DIM + a] = (wv[j] - m) * r * ln_g[c] + ln_b[c];  // [c][a]
        }
    }
}

// ---------------------------------------------------------------------------
// Kernel 3: logits[b][a] = new_x[b,:] . wn[:,a] + bias[a]; softmax over a.
// One block per b; 64 lanes: lane = a + 16*chunk, each lane does 128 MACs,
// combine chunks via shfl_xor(16|32), softmax within 16-lane subgroups.
// ---------------------------------------------------------------------------
__global__ __launch_bounds__(64) void matmul_softmax(
    const float* __restrict__ newx, const float* __restrict__ wn_t,
    const float* __restrict__ rbias,
    float* __restrict__ logits, float* __restrict__ probs) {
    const int b = blockIdx.x;
    const int lane = threadIdx.x;
    const int a = lane & 15;
    const int chunk = lane >> 4;
    const float* xr = newx + b * C_DIM + chunk * 128;
    const float* wr = wn_t + (chunk * 128) * A_DIM + a;
    float acc = 0.f;
#pragma unroll 8
    for (int i = 0; i < 128; i++) {
        acc += xr[i] * wr[i * A_DIM];
    }
    acc += __shfl_xor(acc, 16);
    acc += __shfl_xor(acc, 32);
    const float logit = acc + rbias[a];
    float mx = logit;
#pragma unroll
    for (int m = 1; m < 16; m <<= 1) mx = fmaxf(mx, __shfl_xor(mx, m));
    const float e = expf(logit - mx);
    float se = e;
#pragma unroll
    for (int m = 1; m < 16; m <<= 1) se += __shfl_xor(se, m);
    const float prob = e / se;
    if (lane < 16) {                                 // lane == a here
        logits[b * A_DIM + lane] = logit;
        probs[b * A_DIM + lane] = prob;
    }
}

extern "C" void kernel_launch(void* const* d_in, const int* in_sizes, int n_in,
                              void* d_out, int out_size, void* d_ws, size_t ws_size,
                              hipStream_t stream) {
    const float* x     = (const float*)d_in[0];   // [B,C,H,W]
    const float* rw    = (const float*)d_in[1];   // [1,C,A]
    const float* rbias = (const float*)d_in[2];   // [1,A]
    const float* bn_g  = (const float*)d_in[3];   // [1,C]
    const float* bn_b  = (const float*)d_in[4];
    const float* ln_g  = (const float*)d_in[5];
    const float* ln_b  = (const float*)d_in[6];

    float* out    = (float*)d_out;
    float* newx   = out;                          // 32768 floats: new_x [1,64,512]
    float* logits = out + B_DIM * C_DIM;          // 1024 floats
    float* probs  = logits + B_DIM * A_DIM;       // 1024 floats

    float2* sqs  = (float2*)d_ws;                 // 32768 float2  [c][b]{s,q}
    float*  wn_t = (float*)d_ws + 2 * B_DIM * C_DIM;  // 8192 floats [c][a]

    reduce_rows<<<(B_DIM * C_DIM) / 16, 1024, 0, stream>>>(x, sqs);
    stats_newx_ln<<<C_DIM + A_DIM, 64, 0, stream>>>(sqs, bn_g, bn_b, rw,
                                                    ln_g, ln_b, newx, wn_t);
    matmul_softmax<<<B_DIM, 64, 0, stream>>>(newx, wn_t, rbias, logits, probs);
}

// Round 3
// 199.465 us; speedup vs baseline: 2.1661x; 1.0514x over previous
//
#include <hip/hip_runtime.h>

// Problem constants (from reference): B=64, C=512, H=W=32, N=1, A=16
#define B_DIM 64
#define C_DIM 512
#define A_DIM 16
#define HW    1024           // H*W
#define EPS   1e-5f

typedef float f32x4 __attribute__((ext_vector_type(4)));

// ---------------------------------------------------------------------------
// Kernel 1: per-(b,c) row reduction of x (contiguous 1024 floats each).
// One block per (b,c); 256 threads, one float4 per thread (fully coalesced).
// NONTEMPORAL loads on x: on miss, do NOT allocate in L2/L3 -> avoids
// evicting the 256MB of dirty lines the harness's 512MiB workspace fill
// left in the Infinity Cache (writeback traffic was throttling our read).
// Writes sqs[c*B + b] = {sum, sumsq} as one float2 (8B) store.
// ---------------------------------------------------------------------------
__global__ __launch_bounds__(256) void reduce_rows(const float* __restrict__ x,
                                                   float2* __restrict__ sqs) {
    const int bc = blockIdx.x;                       // = b*C + c (matches x layout)
    const f32x4* p = reinterpret_cast<const f32x4*>(x + (size_t)bc * HW);
    const f32x4 v = __builtin_nontemporal_load(p + threadIdx.x);
    float s = v[0] + v[1] + v[2] + v[3];
    float q = v[0] * v[0] + v[1] * v[1] + v[2] * v[2] + v[3] * v[3];
#pragma unroll
    for (int off = 32; off > 0; off >>= 1) {
        s += __shfl_down(s, off);
        q += __shfl_down(q, off);
    }
    __shared__ float ls[4], lq[4];
    const int wid = threadIdx.x >> 6;
    const int lane = threadIdx.x & 63;
    if (lane == 0) { ls[wid] = s; lq[wid] = q; }
    __syncthreads();
    if (threadIdx.x == 0) {
        s = ls[0] + ls[1] + ls[2] + ls[3];
        q = lq[0] + lq[1] + lq[2] + lq[3];
        const int b = bc >> 9;                       // bc / C_DIM
        const int c = bc & (C_DIM - 1);
        sqs[c * B_DIM + b] = make_float2(s, q);      // [c][b] -> coalesced in K2
    }
}

// ---------------------------------------------------------------------------
// Kernel 2: blocks [0,512): per-channel batch stats + new_x.
//           blocks [512,528): LayerNorm of router_weights^T rows -> wn_t[c][a].
// 64 threads = 1 wave per block.
// ---------------------------------------------------------------------------
__global__ __launch_bounds__(64) void stats_newx_ln(
    const float2* __restrict__ sqs,
    const float* __restrict__ bn_g, const float* __restrict__ bn_b,
    const float* __restrict__ rw, const float* __restrict__ ln_g,
    const float* __restrict__ ln_b,
    float* __restrict__ newx, float* __restrict__ wn_t) {
    const int lane = threadIdx.x;
    if (blockIdx.x < C_DIM) {
        // --- batch-norm stats for channel c + pooled new_x ---
        const int c = blockIdx.x;
        const float2 v = sqs[c * B_DIM + lane];      // lane == b, 8B coalesced
        float ts = v.x, tq = v.y;
#pragma unroll
        for (int off = 32; off > 0; off >>= 1) {
            ts += __shfl_down(ts, off);
            tq += __shfl_down(tq, off);
        }
        const float mu  = __shfl(ts, 0) * (1.0f / 65536.0f);   // /(B*H*W)
        const float var = __shfl(tq, 0) * (1.0f / 65536.0f) - mu * mu;
        const float r   = rsqrtf(var + EPS);
        const float nx  = bn_g[c] * (v.x * (1.0f / 1024.0f) - mu) * r + bn_b[c];
        newx[lane * C_DIM + c] = nx;                 // new_x[b][c]
    } else {
        // --- LayerNorm over C of router_weights[:,a] (i.e. W^T row a) ---
        const int a = blockIdx.x - C_DIM;
        float wv[8];
        float s = 0.f, q = 0.f;
#pragma unroll
        for (int j = 0; j < 8; j++) {
            const int c = j * 64 + lane;
            wv[j] = rw[c * A_DIM + a];
            s += wv[j];
            q += wv[j] * wv[j];
        }
#pragma unroll
        for (int off = 32; off > 0; off >>= 1) {
            s += __shfl_down(s, off);
            q += __shfl_down(q, off);
        }
        const float m = __shfl(s, 0) * (1.0f / 512.0f);
        const float v = __shfl(q, 0) * (1.0f / 512.0f) - m * m;
        const float r = rsqrtf(v + EPS);
#pragma unroll
        for (int j = 0; j < 8; j++) {
            const int c = j * 64 + lane;
            wn_t[c * A_DIM + a] = (wv[j] - m) * r * ln_g[c] + ln_b[c];  // [c][a]
        }
    }
}

// ---------------------------------------------------------------------------
// Kernel 3: logits[b][a] = new_x[b,:] . wn[:,a] + bias[a]; softmax over a.
// One block per b; 64 lanes: lane = a + 16*chunk, each lane does 128 MACs,
// combine chunks via shfl_xor(16|32), softmax within 16-lane subgroups.
// ---------------------------------------------------------------------------
__global__ __launch_bounds__(64) void matmul_softmax(
    const float* __restrict__ newx, const float* __restrict__ wn_t,
    const float* __restrict__ rbias,
    float* __restrict__ logits, float* __restrict__ probs) {
    const int b = blockIdx.x;
    const int lane = threadIdx.x;
    const int a = lane & 15;
    const int chunk = lane >> 4;
    const float* xr = newx + b * C_DIM + chunk * 128;
    const float* wr = wn_t + (chunk * 128) * A_DIM + a;
    float acc = 0.f;
#pragma unroll 8
    for (int i = 0; i < 128; i++) {
        acc += xr[i] * wr[i * A_DIM];
    }
    acc += __shfl_xor(acc, 16);
    acc += __shfl_xor(acc, 32);
    const float logit = acc + rbias[a];
    float mx = logit;
#pragma unroll
    for (int m = 1; m < 16; m <<= 1) mx = fmaxf(mx, __shfl_xor(mx, m));
    const float e = expf(logit - mx);
    float se = e;
#pragma unroll
    for (int m = 1; m < 16; m <<= 1) se += __shfl_xor(se, m);
    const float prob = e / se;
    if (lane < 16) {                                 // lane == a here
        logits[b * A_DIM + lane] = logit;
        probs[b * A_DIM + lane] = prob;
    }
}

extern "C" void kernel_launch(void* const* d_in, const int* in_sizes, int n_in,
                              void* d_out, int out_size, void* d_ws, size_t ws_size,
                              hipStream_t stream) {
    const float* x     = (const float*)d_in[0];   // [B,C,H,W]
    const float* rw    = (const float*)d_in[1];   // [1,C,A]
    const float* rbias = (const float*)d_in[2];   // [1,A]
    const float* bn_g  = (const float*)d_in[3];   // [1,C]
    const float* bn_b  = (const float*)d_in[4];
    const float* ln_g  = (const float*)d_in[5];
    const float* ln_b  = (const float*)d_in[6];

    float* out    = (float*)d_out;
    float* newx   = out;                          // 32768 floats: new_x [1,64,512]
    float* logits = out + B_DIM * C_DIM;          // 1024 floats
    float* probs  = logits + B_DIM * A_DIM;       // 1024 floats

    float2* sqs  = (float2*)d_ws;                 // 32768 float2  [c][b]{s,q}
    float*  wn_t = (float*)d_ws + 2 * B_DIM * C_DIM;  // 8192 floats [c][a]

    reduce_rows<<<B_DIM * C_DIM, 256, 0, stream>>>(x, sqs);
    stats_newx_ln<<<C_DIM + A_DIM, 64, 0, stream>>>(sqs, bn_g, bn_b, rw,
                                                    ln_g, ln_b, newx, wn_t);
    matmul_softmax<<<B_DIM, 64, 0, stream>>>(newx, wn_t, rbias, logits, probs);
}

// Round 4
// 195.993 us; speedup vs baseline: 2.2045x; 1.0177x over previous
//
#include <hip/hip_runtime.h>

// Problem constants (from reference): B=64, C=512, H=W=32, N=1, A=16
#define B_DIM 64
#define C_DIM 512
#define A_DIM 16
#define HW    1024           // H*W
#define EPS   1e-5f

typedef float f32x4 __attribute__((ext_vector_type(4)));

// ---------------------------------------------------------------------------
// Kernel 1: per-(b,c) row reduction of x (contiguous 1024 floats each).
// 256-thread blocks (4 waves, 8 blocks/CU resident); each WAVE owns TWO
// adjacent rows -> 8 independent nontemporal float4 loads per lane (ILP 8,
// 128 B in flight/lane) followed by two interleaved 6-level shfl reductions.
// No LDS, no __syncthreads, no serial epilogue. Grid 4096 (was 32768).
// nt loads: avoid allocating x in L2/L3 over the harness fill's dirty lines.
// Writes sqs[c*B + b] = {sum, sumsq} (8B store per row by lane 0).
// ---------------------------------------------------------------------------
__global__ __launch_bounds__(256) void reduce_rows(const float* __restrict__ x,
                                                   float2* __restrict__ sqs) {
    const int wid  = threadIdx.x >> 6;               // 0..3
    const int lane = threadIdx.x & 63;
    const int rA   = blockIdx.x * 8 + wid * 2;       // rows rA, rA+1  (= b*C+c)
    const f32x4* pA = reinterpret_cast<const f32x4*>(x + (size_t)rA * HW);
    const f32x4* pB = pA + (HW / 4);                 // next row

    f32x4 va[4], vb[4];
#pragma unroll
    for (int j = 0; j < 4; ++j) va[j] = __builtin_nontemporal_load(pA + lane + 64 * j);
#pragma unroll
    for (int j = 0; j < 4; ++j) vb[j] = __builtin_nontemporal_load(pB + lane + 64 * j);

    float sa = 0.f, qa = 0.f, sb = 0.f, qb = 0.f;
#pragma unroll
    for (int j = 0; j < 4; ++j) {
        sa += va[j][0] + va[j][1] + va[j][2] + va[j][3];
        qa += va[j][0] * va[j][0] + va[j][1] * va[j][1]
            + va[j][2] * va[j][2] + va[j][3] * va[j][3];
        sb += vb[j][0] + vb[j][1] + vb[j][2] + vb[j][3];
        qb += vb[j][0] * vb[j][0] + vb[j][1] * vb[j][1]
            + vb[j][2] * vb[j][2] + vb[j][3] * vb[j][3];
    }
#pragma unroll
    for (int off = 32; off > 0; off >>= 1) {         // two independent chains
        sa += __shfl_down(sa, off);
        qa += __shfl_down(qa, off);
        sb += __shfl_down(sb, off);
        qb += __shfl_down(qb, off);
    }
    if (lane == 0) {
        const int rB = rA + 1;
        sqs[(rA & (C_DIM - 1)) * B_DIM + (rA >> 9)] = make_float2(sa, qa);
        sqs[(rB & (C_DIM - 1)) * B_DIM + (rB >> 9)] = make_float2(sb, qb);
    }
}

// ---------------------------------------------------------------------------
// Kernel 2: blocks [0,512): per-channel batch stats + new_x.
//           blocks [512,528): LayerNorm of router_weights^T rows -> wn_t[c][a].
// 64 threads = 1 wave per block.
// ---------------------------------------------------------------------------
__global__ __launch_bounds__(64) void stats_newx_ln(
    const float2* __restrict__ sqs,
    const float* __restrict__ bn_g, const float* __restrict__ bn_b,
    const float* __restrict__ rw, const float* __restrict__ ln_g,
    const float* __restrict__ ln_b,
    float* __restrict__ newx, float* __restrict__ wn_t) {
    const int lane = threadIdx.x;
    if (blockIdx.x < C_DIM) {
        // --- batch-norm stats for channel c + pooled new_x ---
        const int c = blockIdx.x;
        const float2 v = sqs[c * B_DIM + lane];      // lane == b, 8B coalesced
        float ts = v.x, tq = v.y;
#pragma unroll
        for (int off = 32; off > 0; off >>= 1) {
            ts += __shfl_down(ts, off);
            tq += __shfl_down(tq, off);
        }
        const float mu  = __shfl(ts, 0) * (1.0f / 65536.0f);   // /(B*H*W)
        const float var = __shfl(tq, 0) * (1.0f / 65536.0f) - mu * mu;
        const float r   = rsqrtf(var + EPS);
        const float nx  = bn_g[c] * (v.x * (1.0f / 1024.0f) - mu) * r + bn_b[c];
        newx[lane * C_DIM + c] = nx;                 // new_x[b][c]
    } else {
        // --- LayerNorm over C of router_weights[:,a] (i.e. W^T row a) ---
        const int a = blockIdx.x - C_DIM;
        float wv[8];
        float s = 0.f, q = 0.f;
#pragma unroll
        for (int j = 0; j < 8; j++) {
            const int c = j * 64 + lane;
            wv[j] = rw[c * A_DIM + a];
            s += wv[j];
            q += wv[j] * wv[j];
        }
#pragma unroll
        for (int off = 32; off > 0; off >>= 1) {
            s += __shfl_down(s, off);
            q += __shfl_down(q, off);
        }
        const float m = __shfl(s, 0) * (1.0f / 512.0f);
        const float v = __shfl(q, 0) * (1.0f / 512.0f) - m * m;
        const float r = rsqrtf(v + EPS);
#pragma unroll
        for (int j = 0; j < 8; j++) {
            const int c = j * 64 + lane;
            wn_t[c * A_DIM + a] = (wv[j] - m) * r * ln_g[c] + ln_b[c];  // [c][a]
        }
    }
}

// ---------------------------------------------------------------------------
// Kernel 3: logits[b][a] = new_x[b,:] . wn[:,a] + bias[a]; softmax over a.
// One block per b; 64 lanes: lane = a + 16*chunk, each lane does 128 MACs,
// combine chunks via shfl_xor(16|32), softmax within 16-lane subgroups.
// ---------------------------------------------------------------------------
__global__ __launch_bounds__(64) void matmul_softmax(
    const float* __restrict__ newx, const float* __restrict__ wn_t,
    const float* __restrict__ rbias,
    float* __restrict__ logits, float* __restrict__ probs) {
    const int b = blockIdx.x;
    const int lane = threadIdx.x;
    const int a = lane & 15;
    const int chunk = lane >> 4;
    const float* xr = newx + b * C_DIM + chunk * 128;
    const float* wr = wn_t + (chunk * 128) * A_DIM + a;
    float acc = 0.f;
#pragma unroll 8
    for (int i = 0; i < 128; i++) {
        acc += xr[i] * wr[i * A_DIM];
    }
    acc += __shfl_xor(acc, 16);
    acc += __shfl_xor(acc, 32);
    const float logit = acc + rbias[a];
    float mx = logit;
#pragma unroll
    for (int m = 1; m < 16; m <<= 1) mx = fmaxf(mx, __shfl_xor(mx, m));
    const float e = expf(logit - mx);
    float se = e;
#pragma unroll
    for (int m = 1; m < 16; m <<= 1) se += __shfl_xor(se, m);
    const float prob = e / se;
    if (lane < 16) {                                 // lane == a here
        logits[b * A_DIM + lane] = logit;
        probs[b * A_DIM + lane] = prob;
    }
}

extern "C" void kernel_launch(void* const* d_in, const int* in_sizes, int n_in,
                              void* d_out, int out_size, void* d_ws, size_t ws_size,
                              hipStream_t stream) {
    const float* x     = (const float*)d_in[0];   // [B,C,H,W]
    const float* rw    = (const float*)d_in[1];   // [1,C,A]
    const float* rbias = (const float*)d_in[2];   // [1,A]
    const float* bn_g  = (const float*)d_in[3];   // [1,C]
    const float* bn_b  = (const float*)d_in[4];
    const float* ln_g  = (const float*)d_in[5];
    const float* ln_b  = (const float*)d_in[6];

    float* out    = (float*)d_out;
    float* newx   = out;                          // 32768 floats: new_x [1,64,512]
    float* logits = out + B_DIM * C_DIM;          // 1024 floats
    float* probs  = logits + B_DIM * A_DIM;       // 1024 floats

    float2* sqs  = (float2*)d_ws;                 // 32768 float2  [c][b]{s,q}
    float*  wn_t = (float*)d_ws + 2 * B_DIM * C_DIM;  // 8192 floats [c][a]

    reduce_rows<<<(B_DIM * C_DIM) / 8, 256, 0, stream>>>(x, sqs);
    stats_newx_ln<<<C_DIM + A_DIM, 64, 0, stream>>>(sqs, bn_g, bn_b, rw,
                                                    ln_g, ln_b, newx, wn_t);
    matmul_softmax<<<B_DIM, 64, 0, stream>>>(newx, wn_t, rbias, logits, probs);
}